// Round 3
// baseline (620.080 us; speedup 1.0000x reference)
//
#include <hip/hip_runtime.h>

// IndRNN (recurrent-only): h_t = relu(x_t + w_hh * h_{t-1})
// x: [T=2048, B=64, H=512] fp32, weight_hh: [H] fp32, out: [T, B, H] fp32.
//
// Round-3 structure: back to the minimal-traffic decomposition (one pass over
// x, one over out, NO scan / re-read), but with 4 chains per thread so every
// global access is a float4 (1 KB per wave-instruction).
//
// Evidence driving this (rounds 0-2): time = memory-system bytes / ~4.6 TB/s
// for dword (4 B/lane) accesses regardless of occupancy (round 2: 32 waves/CU
// was NOT faster than 2 waves/CU in round 0; scan's 1.5x traffic cost exactly
// 1.5x time). So: minimize bytes (drop the scan) and raise the rate ceiling
// (float4 granularity, the m13 6.29 TB/s pattern).
//
// 32768 chains / 4 = 8192 threads = 128 waves. Each thread runs 4 independent
// exact recurrences (ILP-4 fills the fmaf->fmaxf latency), double-buffered
// DEPTH=16 float4 prefetch: 16 KB reads in flight per wave x 128 waves = 2 MB
// ~= Little's-law requirement at 6.3 TB/s x ~375 ns. Semantics are bit-exact
// vs reference (same op order per chain) -> absmax 0.

#define HIDDEN 512
#define SEQ 2048
#define BATCH 64

typedef float f4 __attribute__((ext_vector_type(4)));

constexpr int NCHAIN = BATCH * HIDDEN;  // 32768 chains
constexpr int NQUAD = NCHAIN / 4;       // 8192 threads, one per 4 chains
constexpr int STRIDE4 = NCHAIN / 4;     // f4-elements between t and t+1
constexpr int DEPTH = 16;               // prefetch depth per buffer

template <bool PF>
__device__ __forceinline__ void run_chunk(f4& h, const f4 wh,
                                          const f4 (&cur)[DEPTH],
                                          f4 (&nxt)[DEPTH],
                                          const f4* __restrict__ xn,
                                          f4* __restrict__ o) {
#pragma unroll
  for (int i = 0; i < DEPTH; ++i) {
    if (PF) nxt[i] = __builtin_nontemporal_load(xn + (long)i * STRIDE4);
    const f4 xv = cur[i];
    h.x = fmaxf(0.0f, fmaf(wh.x, h.x, xv.x));  // 4 independent exact chains
    h.y = fmaxf(0.0f, fmaf(wh.y, h.y, xv.y));
    h.z = fmaxf(0.0f, fmaf(wh.z, h.z, xv.z));
    h.w = fmaxf(0.0f, fmaf(wh.w, h.w, xv.w));
    __builtin_nontemporal_store(h, o + (long)i * STRIDE4);
  }
}

__global__ __launch_bounds__(64) void indrnn4(const float* __restrict__ x,
                                              const float* __restrict__ w,
                                              float* __restrict__ out) {
  const int q = blockIdx.x * 64 + threadIdx.x;  // quad-chain id, 0..8191
  // 4 chains of this thread: flat indices 4q..4q+3; h = flat & 511.
  // Quads never straddle the HIDDEN boundary (4 | 512).
  const f4 wh = ((const f4*)w)[q & (HIDDEN / 4 - 1)];
  const f4* xp = (const f4*)x + q;
  f4* op = (f4*)out + q;

  f4 bufA[DEPTH], bufB[DEPTH];
#pragma unroll
  for (int i = 0; i < DEPTH; ++i)
    bufA[i] = __builtin_nontemporal_load(xp + (long)i * STRIDE4);

  f4 hv = {0.0f, 0.0f, 0.0f, 0.0f};
  int t = 0;
#pragma unroll 1
  for (; t + 2 * DEPTH < SEQ; t += 2 * DEPTH) {
    run_chunk<true>(hv, wh, bufA, bufB, xp + (long)(t + DEPTH) * STRIDE4,
                    op + (long)t * STRIDE4);
    run_chunk<true>(hv, wh, bufB, bufA, xp + (long)(t + 2 * DEPTH) * STRIDE4,
                    op + (long)(t + DEPTH) * STRIDE4);
  }
  // Tail pair: first half prefetches the final chunk, second half none.
  run_chunk<true>(hv, wh, bufA, bufB, xp + (long)(t + DEPTH) * STRIDE4,
                  op + (long)t * STRIDE4);
  run_chunk<false>(hv, wh, bufB, bufA, nullptr,
                   op + (long)(t + DEPTH) * STRIDE4);
}

extern "C" void kernel_launch(void* const* d_in, const int* in_sizes, int n_in,
                              void* d_out, int out_size, void* d_ws,
                              size_t ws_size, hipStream_t stream) {
  const float* x = (const float*)d_in[0];
  const float* w = (const float*)d_in[1];
  float* out = (float*)d_out;
  indrnn4<<<NQUAD / 64, 64, 0, stream>>>(x, w, out);
}

// Round 4
// 466.891 us; speedup vs baseline: 1.3281x; 1.3281x over previous
//
#include <hip/hip_runtime.h>

// IndRNN (recurrent-only): h_t = relu(x_t + w_hh * h_{t-1})
// x: [T=2048, B=64, H=512] fp32, weight_hh: [H] fp32 (~uniform[0,1) => w >= 0).
//
// Round-4 synthesis of rounds 0-3 evidence:
//   - effective mem rate scales with wave count up to ~512+ waves, saturating
//     ~4.5 TB/s for dword accesses (R0/R1/R2); 128 waves is latency-starved
//     regardless of access width (R3: f4 @ 128 waves = 1.8 TB/s).
//   - float4 granularity is required to exceed ~4.5 TB/s (m13: 6.29 TB/s).
//   - the scan's phase-2 x re-read is L3-absorbed (R1/R2: FETCH ~235 MB).
// => the only untested quadrant is {float4 x many waves}: scan decomposition
//    with 4 chains/thread. W=16 windows x 8192 quad-threads = 2048 waves.
//
// Scan identity (w >= 0): f_t(h) = max(0, x_t + w*h) composes inside
// F(h) = max(C, B + S*h), C,S >= 0:
//   C' = max(0, x_t + w*C); B' = x_t + w*B; S = w^LWIN (7 squarings).
// phase 1: wave wv accumulates (C,B) for its window   [cached reads: warm L3]
//          wave 0 knows h_start=0 -> writes exact outputs directly
// LDS scan: h_start(wv) = F_{wv-1}(...F_0(0))          [<=15 composes]
// phase 2: exact recurrence (fmaxf(0,fmaf(w,h,x))) from h_start  [NT re-read]
//
// 128 blocks x 1024 thr (16 waves = one quad-group x all windows; scan stays
// intra-block). 16 waves/CU on 128 CUs: per-CU HBM demand ~18 B/cy << L1 path.
// In-flight: 2048 waves x DEPTH(8) x 16B x 64 = 16 MB >> latency product.

#define HIDDEN 512
#define SEQ 2048
#define BATCH 64

typedef float f4 __attribute__((ext_vector_type(4)));

constexpr int NCHAIN = BATCH * HIDDEN;  // 32768 chains
constexpr int NQUAD = NCHAIN / 4;       // 8192 quad-chains
constexpr int S4 = NQUAD;               // f4-elements between t and t+1
constexpr int W = 16;                   // windows per chain = waves per block
constexpr int BLOCK = W * 64;           // 1024 threads
constexpr int LWIN = SEQ / W;           // 128 timesteps per window
constexpr int DEPTH = 8;                // prefetch depth per buffer (f4)

__device__ __forceinline__ f4 step4(const f4 h, const f4 wh, const f4 xv) {
  f4 r;
  r.x = fmaxf(0.0f, fmaf(wh.x, h.x, xv.x));  // exact reference op order
  r.y = fmaxf(0.0f, fmaf(wh.y, h.y, xv.y));
  r.z = fmaxf(0.0f, fmaf(wh.z, h.z, xv.z));
  r.w = fmaxf(0.0f, fmaf(wh.w, h.w, xv.w));
  return r;
}

// Reference-exact recurrence + NT store (wave 0 phase 1, and phase 2).
template <bool PF>
__device__ __forceinline__ void rec_chunk(f4& hv, const f4 wh,
                                          const f4 (&cur)[DEPTH],
                                          f4 (&nxt)[DEPTH],
                                          const f4* __restrict__ xn,
                                          f4* __restrict__ o) {
#pragma unroll
  for (int i = 0; i < DEPTH; ++i) {
    if (PF) nxt[i] = __builtin_nontemporal_load(xn + (long)i * S4);
    hv = step4(hv, wh, cur[i]);
    __builtin_nontemporal_store(hv, o + (long)i * S4);
  }
}

// Composite accumulation: (C,B) <- step(x) o (C,B). Cached loads so the
// phase-2 re-read hits L3 (proven R1/R2: FETCH < one full x pass).
template <bool PF>
__device__ __forceinline__ void comp_chunk(f4& C, f4& Bv, const f4 wh,
                                           const f4 (&cur)[DEPTH],
                                           f4 (&nxt)[DEPTH],
                                           const f4* __restrict__ xn) {
#pragma unroll
  for (int i = 0; i < DEPTH; ++i) {
    if (PF) nxt[i] = xn[(long)i * S4];
    const f4 xv = cur[i];
    C = step4(C, wh, xv);
    Bv.x = fmaf(wh.x, Bv.x, xv.x);
    Bv.y = fmaf(wh.y, Bv.y, xv.y);
    Bv.z = fmaf(wh.z, Bv.z, xv.z);
    Bv.w = fmaf(wh.w, Bv.w, xv.w);
  }
}

__global__ __launch_bounds__(BLOCK, 4) void indrnn_scan4(
    const float* __restrict__ x, const float* __restrict__ w,
    float* __restrict__ out) {
  __shared__ f4 sC[W][64];
  __shared__ f4 sB[W][64];

  const int lane = threadIdx.x & 63;
  const int wv = threadIdx.x >> 6;          // window index 0..15
  const int q = blockIdx.x * 64 + lane;     // quad-chain id (4 chains each)
  const f4 wh = ((const f4*)w)[q & (HIDDEN / 4 - 1)];  // 4 | HIDDEN: no straddle

  const long base = (long)(wv * LWIN) * S4 + q;
  const f4* xp = (const f4*)x + base;
  f4* op = (f4*)out + base;

  f4 bufA[DEPTH], bufB[DEPTH];
  const f4 z4 = {0.0f, 0.0f, 0.0f, 0.0f};

  if (wv == 0) {
    // Window 0 data is read exactly once -> NT loads throughout.
#pragma unroll
    for (int i = 0; i < DEPTH; ++i)
      bufA[i] = __builtin_nontemporal_load(xp + (long)i * S4);
    f4 hv = z4;
    int t = 0;
#pragma unroll 1
    for (; t + 2 * DEPTH < LWIN; t += 2 * DEPTH) {
      rec_chunk<true>(hv, wh, bufA, bufB, xp + (long)(t + DEPTH) * S4,
                      op + (long)t * S4);
      rec_chunk<true>(hv, wh, bufB, bufA, xp + (long)(t + 2 * DEPTH) * S4,
                      op + (long)(t + DEPTH) * S4);
    }
    rec_chunk<true>(hv, wh, bufA, bufB, xp + (long)(t + DEPTH) * S4,
                    op + (long)t * S4);
    rec_chunk<false>(hv, wh, bufB, bufA, nullptr,
                     op + (long)(t + DEPTH) * S4);
    sC[0][lane] = hv;  // F_0(0): scan seed for waves 1..
  } else {
#pragma unroll
    for (int i = 0; i < DEPTH; ++i) bufA[i] = xp[(long)i * S4];
    f4 C = z4, Bv = z4;
    int t = 0;
#pragma unroll 1
    for (; t + 2 * DEPTH < LWIN; t += 2 * DEPTH) {
      comp_chunk<true>(C, Bv, wh, bufA, bufB, xp + (long)(t + DEPTH) * S4);
      comp_chunk<true>(C, Bv, wh, bufB, bufA, xp + (long)(t + 2 * DEPTH) * S4);
    }
    comp_chunk<true>(C, Bv, wh, bufA, bufB, xp + (long)(t + DEPTH) * S4);
    comp_chunk<false>(C, Bv, wh, bufB, bufA, nullptr);

    // Prime phase-2 loads before the barrier: latency hides under the
    // barrier + scan. Last use of this data -> nontemporal.
#pragma unroll
    for (int i = 0; i < DEPTH; ++i)
      bufA[i] = __builtin_nontemporal_load(xp + (long)i * S4);

    sC[wv][lane] = C;
    sB[wv][lane] = Bv;
  }

  __syncthreads();  // convergent: every thread reaches exactly this barrier

  if (wv == 0) return;

  // S = wh^LWIN (LWIN = 128 = 2^7) by 7 squarings - window-independent.
  f4 Sp = wh;
#pragma unroll
  for (int k = 0; k < 7; ++k) {
    Sp.x *= Sp.x; Sp.y *= Sp.y; Sp.z *= Sp.z; Sp.w *= Sp.w;
  }

  // Scan predecessors' composites to get this window's true h_start.
  f4 hv = sC[0][lane];
  for (int k = 1; k < wv; ++k) {
    const f4 c = sC[k][lane], b = sB[k][lane];
    hv.x = fmaxf(c.x, fmaf(Sp.x, hv.x, b.x));
    hv.y = fmaxf(c.y, fmaf(Sp.y, hv.y, b.y));
    hv.z = fmaxf(c.z, fmaf(Sp.z, hv.z, b.z));
    hv.w = fmaxf(c.w, fmaf(Sp.w, hv.w, b.w));
  }

  // Phase 2: exact recurrence from h_start, write outputs.
  int t = 0;
#pragma unroll 1
  for (; t + 2 * DEPTH < LWIN; t += 2 * DEPTH) {
    rec_chunk<true>(hv, wh, bufA, bufB, xp + (long)(t + DEPTH) * S4,
                    op + (long)t * S4);
    rec_chunk<true>(hv, wh, bufB, bufA, xp + (long)(t + 2 * DEPTH) * S4,
                    op + (long)(t + DEPTH) * S4);
  }
  rec_chunk<true>(hv, wh, bufA, bufB, xp + (long)(t + DEPTH) * S4,
                  op + (long)t * S4);
  rec_chunk<false>(hv, wh, bufB, bufA, nullptr,
                   op + (long)(t + DEPTH) * S4);
}

extern "C" void kernel_launch(void* const* d_in, const int* in_sizes, int n_in,
                              void* d_out, int out_size, void* d_ws,
                              size_t ws_size, hipStream_t stream) {
  const float* x = (const float*)d_in[0];
  const float* w = (const float*)d_in[1];
  float* out = (float*)d_out;
  indrnn_scan4<<<NQUAD / 64, BLOCK, 0, stream>>>(x, w, out);
}

// Round 5
// 422.255 us; speedup vs baseline: 1.4685x; 1.1057x over previous
//
#include <hip/hip_runtime.h>

// IndRNN (recurrent-only): h_t = relu(x_t + w_hh * h_{t-1})
// x: [T=2048, B=64, H=512] fp32, weight_hh: [H] fp32, out: [T, B, H] fp32.
//
// Round-5: minimal-traffic structure (R0) with ONE change: cached stores.
//
// Evidence (R0-R4): above ~512 waves the memory system serves a flat
// ~4.6 TB/s for this kernel regardless of access width (dword vs float4),
// wave count (512..8192), or active-CU count -> any scan/recompute structure
// loses (its 1.5x traffic cost 1.5x time, measured twice). Minimal traffic
// (536 MB: x once in, out once) is the only winning shape. The one lever left:
// m13's float4 copy (same 1:1 R/W mix) sustains 6.29 TB/s and the harness
// fill writes at 6.5 TB/s -- both through the cache hierarchy -- while R0
// used nontemporal stores (128B fine-grain streamout, fine-grain R/W
// interleave at the controller). Hypothesis: NT stores are the ~30% tax.
// Zero-reuse kernel => cached stores cost nothing in pollution.
//
// Skeleton identical to the 418.5us best: one thread per (b,h) chain,
// 32768 threads = 512 waves, DEPTH=32 double-buffered NT loads (x has no
// reuse; keep it out of L2/L3 so the write stream owns the caches),
// bit-exact reference op order -> absmax 0.

#define HIDDEN 512
#define SEQ 2048
#define BATCH 64

constexpr int NCHAIN = BATCH * HIDDEN;   // 32768 independent chains
constexpr int STRIDE = BATCH * HIDDEN;   // element stride between t and t+1
constexpr int DEPTH = 32;                // prefetch depth per buffer

template <bool PF>
__device__ __forceinline__ void run_chunk(float& hv, const float wh,
                                          const float (&cur)[DEPTH],
                                          float (&nxt)[DEPTH],
                                          const float* __restrict__ xn,
                                          float* __restrict__ o) {
#pragma unroll
  for (int i = 0; i < DEPTH; ++i) {
    if (PF) nxt[i] = __builtin_nontemporal_load(xn + (long)i * STRIDE);
    hv = fmaxf(0.0f, fmaf(wh, hv, cur[i]));  // exact reference op order
    o[(long)i * STRIDE] = hv;                // CACHED store (the one change)
  }
}

__global__ __launch_bounds__(64) void indrnn_kernel(
    const float* __restrict__ x, const float* __restrict__ w,
    float* __restrict__ out) {
  const int idx = blockIdx.x * 64 + threadIdx.x;  // b*H + h
  const float wh = w[idx & (HIDDEN - 1)];
  const float* xp = x + idx;
  float* op = out + idx;

  float bufA[DEPTH], bufB[DEPTH];
#pragma unroll
  for (int i = 0; i < DEPTH; ++i)
    bufA[i] = __builtin_nontemporal_load(xp + (long)i * STRIDE);

  float hv = 0.0f;
  int t = 0;
#pragma unroll 1
  for (; t + 2 * DEPTH < SEQ; t += 2 * DEPTH) {
    run_chunk<true>(hv, wh, bufA, bufB, xp + (long)(t + DEPTH) * STRIDE,
                    op + (long)t * STRIDE);
    run_chunk<true>(hv, wh, bufB, bufA, xp + (long)(t + 2 * DEPTH) * STRIDE,
                    op + (long)(t + DEPTH) * STRIDE);
  }
  // Tail pair: first half still prefetches the final chunk, second half none.
  run_chunk<true>(hv, wh, bufA, bufB, xp + (long)(t + DEPTH) * STRIDE,
                  op + (long)t * STRIDE);
  run_chunk<false>(hv, wh, bufB, bufA, nullptr,
                   op + (long)(t + DEPTH) * STRIDE);
}

extern "C" void kernel_launch(void* const* d_in, const int* in_sizes, int n_in,
                              void* d_out, int out_size, void* d_ws,
                              size_t ws_size, hipStream_t stream) {
  const float* x = (const float*)d_in[0];
  const float* w = (const float*)d_in[1];
  float* out = (float*)d_out;
  indrnn_kernel<<<NCHAIN / 64, 64, 0, stream>>>(x, w, out);
}

// Round 6
// 413.835 us; speedup vs baseline: 1.4984x; 1.0203x over previous
//
#include <hip/hip_runtime.h>

// IndRNN (recurrent-only): h_t = relu(x_t + w_hh * h_{t-1})
// x: [T=2048, B=64, H=512] fp32, weight_hh: [H] fp32, out: [T, B, H] fp32.
//
// Round-6: minimal-traffic structure (R0) with ONE change: stores are widened
// to 512 B/wave-op via an LDS transpose, batched per 32-timestep chunk.
//
// Evidence (R0-R5): this kernel pins at ~4.6 TB/s combined R+W independent of
// wave count (512..8192), access width when traffic is inflated (R4), cache
// mode of stores (R5 neutral), and active-CU count. The one un-isolated
// variable at minimal traffic is per-op width/batching: R0 issues 256 B ops
// with per-timestep R/W interleave and is slot-capped (63 vmcnt slots x
// 256 B x 2 waves/CU = 32 KB/CU in flight; at the measured ~0.9 us loaded
// latency that is exactly ~4.6 TB/s). Everything measured >=6.2 TB/s (fill,
// m13 float4 copy) issues >=512 B ops in same-direction runs.
//
// Loads cannot be widened (a thread needs 1 chain x all t; wide loads give
// N chains x 1 t), so the load side keeps R0's exact pattern. Stores go
// through LDS: compute stages 32 t of h into hs[par], barrier, then each of
// the 2 waves stores its 16 timesteps as dwordx2 (64 lanes x 8 B = 512 B/op,
// full 128-chain row per op). 16 store-ops/chunk/wave instead of 32, issued
// in a burst. One barrier per chunk (64 total). Bit-exact chain -> absmax 0.
//
// Geometry: 256 blocks x 128 threads (2 waves, 128 chains/block) = 512 waves,
// 1 block/CU on all 256 CUs -- same distribution as R0.

#define HIDDEN 512
#define SEQ 2048
#define BATCH 64

typedef float f2 __attribute__((ext_vector_type(2)));

constexpr int STRIDE = BATCH * HIDDEN;  // 32768 floats between t and t+1
constexpr int NCHAIN = BATCH * HIDDEN;  // 32768 chains
constexpr int CPB = 128;                // chains per block (= threads)
constexpr int NBLK = NCHAIN / CPB;      // 256 blocks
constexpr int CHUNK = 32;               // timesteps per chunk (= DEPTH)
constexpr int NCHUNK = SEQ / CHUNK;     // 64 chunks
constexpr int S2 = STRIDE / 2;          // f2 elements between t and t+1

// One chunk: prefetch next chunk's x (dword, NT), run 32 exact recurrence
// steps staging h into LDS, barrier, then wave-wide 512 B store burst.
template <bool PF>
__device__ __forceinline__ void chunk_body(
    const int k, float& hv, const float wh, const float (&cur)[CHUNK],
    float (&nxt)[CHUNK], const float* __restrict__ xn,
    f2* __restrict__ op2, float(*__restrict__ hs)[CHUNK][CPB], const int tid,
    const int wv, const int lane) {
  const int par = k & 1;
#pragma unroll
  for (int i = 0; i < CHUNK; ++i) {
    if (PF) nxt[i] = __builtin_nontemporal_load(xn + (long)i * STRIDE);
    hv = fmaxf(0.0f, fmaf(wh, hv, cur[i]));  // exact reference op order
    hs[par][i][tid] = hv;                    // b32 write, conflict-free
  }
  __syncthreads();  // hs[par] complete; also fences prior-parity reuse
#pragma unroll
  for (int j = 0; j < CHUNK / 2; ++j) {
    const int t = wv * (CHUNK / 2) + j;  // wave wv stores its 16 timesteps
    const f2 v = *(const f2*)&hs[par][t][2 * lane];  // b64, conflict-free
    __builtin_nontemporal_store(v, op2 + (long)(k * CHUNK + t) * S2);
  }
}

__global__ __launch_bounds__(CPB) void indrnn_wide(
    const float* __restrict__ x, const float* __restrict__ w,
    float* __restrict__ out) {
  __shared__ float hs[2][CHUNK][CPB];  // 32 KB, double-buffered by chunk

  const int tid = threadIdx.x;
  const int lane = tid & 63;
  const int wv = tid >> 6;  // 0..1
  const int chain = blockIdx.x * CPB + tid;
  const float wh = w[chain & (HIDDEN - 1)];
  const float* xp = x + chain;
  f2* op2 = (f2*)out + blockIdx.x * (CPB / 2) + lane;

  float bufA[CHUNK], bufB[CHUNK];
#pragma unroll
  for (int i = 0; i < CHUNK; ++i)
    bufA[i] = __builtin_nontemporal_load(xp + (long)i * STRIDE);

  float hv = 0.0f;
  int k = 0;
#pragma unroll 1
  for (; k + 2 < NCHUNK; k += 2) {
    chunk_body<true>(k, hv, wh, bufA, bufB,
                     xp + (long)(k + 1) * CHUNK * STRIDE, op2, hs, tid, wv,
                     lane);
    chunk_body<true>(k + 1, hv, wh, bufB, bufA,
                     xp + (long)(k + 2) * CHUNK * STRIDE, op2, hs, tid, wv,
                     lane);
  }
  // Tail pair: first still prefetches the final chunk, second none.
  chunk_body<true>(k, hv, wh, bufA, bufB, xp + (long)(k + 1) * CHUNK * STRIDE,
                   op2, hs, tid, wv, lane);
  chunk_body<false>(k + 1, hv, wh, bufB, bufA, nullptr, op2, hs, tid, wv,
                    lane);
}

extern "C" void kernel_launch(void* const* d_in, const int* in_sizes, int n_in,
                              void* d_out, int out_size, void* d_ws,
                              size_t ws_size, hipStream_t stream) {
  const float* x = (const float*)d_in[0];
  const float* w = (const float*)d_in[1];
  float* out = (float*)d_out;
  indrnn_wide<<<NBLK, CPB, 0, stream>>>(x, w, out);
}